// Round 9
// baseline (338.303 us; speedup 1.0000x reference)
//
#include <hip/hip_runtime.h>
#include <hip/hip_cooperative_groups.h>

namespace cg = cooperative_groups;

#define D 128
#define TILE_M 64
#define BS_STRIDE 129
#define AS_STRIDE 68
#define WS_STRIDE 136   // shorts; 272 B rows -> 16 B aligned, banks spread
#define DS_STRIDE 136
#define MEGA_BLOCKS 768     // 256 CU x 3 blocks/CU (52 KB LDS) -> cooperative-launchable
#define GEMM_BLOCKS 768     // fallback-path gemm role count
#define CAP 64              // padded CSR row capacity (max degree ~35; 64 = 12 sigma)
#define CSH 9               // coarse bin = dst>>9 (512 nodes/bin); N<=65536 -> <=128 bins
#define CBCAP 16384         // coarse-bin capacity (mean 8163 @ E=800K, ~45 sigma slack)
#define P1_CHUNK 1044       // ceil(800000/768) -> x4; grouped[] = 8352 B LDS

typedef __attribute__((ext_vector_type(8))) short short8;
typedef __attribute__((ext_vector_type(4))) float floatx4;
typedef __attribute__((ext_vector_type(4))) unsigned short ushortx4;

__device__ __forceinline__ unsigned short f2bf(float f) {
    unsigned u = __float_as_uint(f);
    u += 0x7fffu + ((u >> 16) & 1u);   // round-to-nearest-even
    return (unsigned short)(u >> 16);
}

// ================= device-function building blocks (shared by mega + fallback) =================
// r20: r19's per-node src-sort REVERTED (serial LDS insertion sort cost +40us on csr_gemm
// and the gather gained ~nothing -> gather is at ~5.8 TB/s effective, near memory ceiling).
// This round: phase-fuse everything into ONE cooperative kernel to remove the ~25us of
// launch gaps + memset serialization identified in the r7/r8 ledger.

// ---- partition one chunk of edges into coarse dst-bins (LDS radix) ----
// smem layout: hist 0..511 | startb 512..1023 | cursor 1024..1535 | gbase 1536..2047 |
//              grouped 2048..10399   (10.4 KB)
__device__ __forceinline__ void partition_chunk(
    char* smem, const int* __restrict__ src, const int* __restrict__ dst,
    const float* __restrict__ w, int* __restrict__ gcnt,
    uint2* __restrict__ binned, int N, int E, int cidx)
{
    int* hist      = reinterpret_cast<int*>(smem);
    int* startb    = reinterpret_cast<int*>(smem + 512);
    int* cursor    = reinterpret_cast<int*>(smem + 1024);
    int* gbase     = reinterpret_cast<int*>(smem + 1536);
    uint2* grouped = reinterpret_cast<uint2*>(smem + 2048);   // P1_CHUNK*8 B
    const int tid = threadIdx.x;
    const int ncb = (N + 511) >> CSH;
    const int base = cidx * P1_CHUNK;
    int lim = E - base;
    if (lim > P1_CHUNK) lim = P1_CHUNK;
    if (lim < 0) lim = 0;
    const int lim4 = lim & ~3;

    if (tid < 128) hist[tid] = 0;
    __syncthreads();
    for (int i = tid * 4; i < lim4; i += 1024) {
        const int4 d4 = *reinterpret_cast<const int4*>(dst + base + i);
        atomicAdd(&hist[d4.x >> CSH], 1);
        atomicAdd(&hist[d4.y >> CSH], 1);
        atomicAdd(&hist[d4.z >> CSH], 1);
        atomicAdd(&hist[d4.w >> CSH], 1);
    }
    for (int i = lim4 + tid; i < lim; i += 256)
        atomicAdd(&hist[dst[base + i] >> CSH], 1);
    __syncthreads();
    if (tid == 0) {
        int s = 0;
        for (int b = 0; b < ncb; ++b) { startb[b] = s; s += hist[b]; }
    }
    __syncthreads();
    if (tid < ncb) {
        gbase[tid]  = atomicAdd(&gcnt[tid], hist[tid]);   // only global atomics
        cursor[tid] = startb[tid];
    }
    __syncthreads();
    for (int i = tid * 4; i < lim4; i += 1024) {
        const int4   d4 = *reinterpret_cast<const int4*>(dst + base + i);
        const int4   s4 = *reinterpret_cast<const int4*>(src + base + i);
        const float4 w4 = *reinterpret_cast<const float4*>(w + base + i);
#pragma unroll
        for (int j = 0; j < 4; ++j) {
            int   d  = (j == 0) ? d4.x : (j == 1) ? d4.y : (j == 2) ? d4.z : d4.w;
            int   sj = (j == 0) ? s4.x : (j == 1) ? s4.y : (j == 2) ? s4.z : s4.w;
            float wj = (j == 0) ? w4.x : (j == 1) ? w4.y : (j == 2) ? w4.z : w4.w;
            unsigned rec = ((unsigned)f2bf(wj) << 16) | (unsigned)sj;
            int g = atomicAdd(&cursor[d >> CSH], 1);
            grouped[g] = make_uint2((unsigned)d, rec);
        }
    }
    for (int i = lim4 + tid; i < lim; i += 256) {
        int e = base + i;
        int d = dst[e];
        unsigned rec = ((unsigned)f2bf(w[e]) << 16) | (unsigned)src[e];
        int g = atomicAdd(&cursor[d >> CSH], 1);
        grouped[g] = make_uint2((unsigned)d, rec);
    }
    __syncthreads();
    for (int i = tid; i < lim; i += 256) {
        uint2 v = grouped[i];
        int b = (int)(v.x >> CSH);
        int off = gbase[b] + (i - startb[b]);
        if (off < CBCAP)
            binned[(size_t)b * CBCAP + (size_t)off] = v;
    }
    __syncthreads();   // protect smem reuse by caller / next chunk
}

// ---- build plane-major padded CSR for one 128-node fine bin (NO sort) ----
// smem: rowsT 0..32767 | lcnt 32768..33279 | maxcp 33280
__device__ __forceinline__ void csr_build_bin(
    char* smem, const uint2* __restrict__ binned, const int* __restrict__ gcnt,
    unsigned* __restrict__ ep, int* __restrict__ cnt, int N, int fb)
{
    unsigned* rowsT = reinterpret_cast<unsigned*>(smem);
    int* lcnt       = reinterpret_cast<int*>(smem + 32768);
    int* maxcp      = reinterpret_cast<int*>(smem + 32768 + 512);
    const int tid = threadIdx.x;
    const int d0 = fb << 7;
    const int cb = fb >> 2;

    if (tid < 128) lcnt[tid] = 0;
    __syncthreads();
    int len = gcnt[cb];
    len = len < CBCAP ? len : CBCAP;
    const uint2* bp = binned + (size_t)cb * CBCAP;
    const int len2 = len & ~1;
    for (int i = tid * 2; i < len2; i += 512) {     // uint4 = 2 records
        const uint4 v2 = *reinterpret_cast<const uint4*>(bp + i);
        int da = (int)v2.x;
        if ((da >> 7) == fb) {
            int pos = atomicAdd(&lcnt[da & 127], 1);
            if (pos < CAP) rowsT[pos * 128 + (da & 127)] = v2.y;
        }
        int db = (int)v2.z;
        if ((db >> 7) == fb) {
            int pos = atomicAdd(&lcnt[db & 127], 1);
            if (pos < CAP) rowsT[pos * 128 + (db & 127)] = v2.w;
        }
    }
    for (int i = len2 + tid; i < len; i += 256) {
        uint2 v = bp[i];
        int d = (int)v.x;
        if ((d >> 7) == fb) {
            int pos = atomicAdd(&lcnt[d & 127], 1);
            if (pos < CAP) rowsT[pos * 128 + (d & 127)] = v.y;
        }
    }
    __syncthreads();
    if (tid == 0) {
        int m = 0;
        for (int j = 0; j < 128; ++j) m = m > lcnt[j] ? m : lcnt[j];
        *maxcp = m < CAP ? m : CAP;
    }
    __syncthreads();
    const int pu = *maxcp;
    for (int idx = tid; idx < (pu << 7); idx += 256) {
        int p = idx >> 7, j = idx & 127;
        int d = d0 + j;
        if (d < N) ep[(size_t)p * N + d] = rowsT[idx];   // 512B runs, coalesced
    }
    if (tid < 128) {
        int d = d0 + tid;
        if (d < N) cnt[d] = lcnt[tid];
    }
    __syncthreads();   // all rowsT readers done before caller reuses smem
}

// ---- stage W (bf16) into LDS ----
__device__ __forceinline__ void gemm_stage_W(char* smem, const float* __restrict__ Wm)
{
    unsigned short* Ws = reinterpret_cast<unsigned short*>(smem);
    for (int idx = threadIdx.x; idx < 128 * 128 / 4; idx += 256) {
        int r = idx >> 5;
        int c = (idx & 31) * 4;
        const float4 v = reinterpret_cast<const float4*>(Wm)[idx];
        ushortx4 s;
        s[0] = f2bf(v.x); s[1] = f2bf(v.y); s[2] = f2bf(v.z); s[3] = f2bf(v.w);
        *reinterpret_cast<ushortx4*>(&Ws[r * WS_STRIDE + c]) = s;
    }
    __syncthreads();
}

// ---- one 64-node MFMA tile: tf[node0..node0+63] = bf16(feat @ W^T) ----
__device__ __forceinline__ void gemm_tile(
    char* smem, const float* __restrict__ feat,
    unsigned short* __restrict__ tf, int N, int t)
{
    unsigned short* Ws = reinterpret_cast<unsigned short*>(smem);
    unsigned short* Ds = reinterpret_cast<unsigned short*>(smem + 34816);
    const int tid = threadIdx.x;
    const int lane = tid & 63;
    const int wave = tid >> 6;
    const int kq = (lane >> 4) * 8;
    const int node0 = t * 64;
    const int mr = node0 + wave * 16 + (lane & 15);
    const float* arow = feat + (size_t)(mr < N ? mr : (N - 1)) * D + kq;

    short8 a[4];
#pragma unroll
    for (int kt = 0; kt < 4; ++kt) {
        const float* p = arow + kt * 32;
        const float4 lo = *reinterpret_cast<const float4*>(p);
        const float4 hi = *reinterpret_cast<const float4*>(p + 4);
        short8 v;
        v[0] = (short)f2bf(lo.x); v[1] = (short)f2bf(lo.y);
        v[2] = (short)f2bf(lo.z); v[3] = (short)f2bf(lo.w);
        v[4] = (short)f2bf(hi.x); v[5] = (short)f2bf(hi.y);
        v[6] = (short)f2bf(hi.z); v[7] = (short)f2bf(hi.w);
        a[kt] = v;
    }

    floatx4 acc[8];
#pragma unroll
    for (int nt = 0; nt < 8; ++nt) {
        acc[nt][0] = 0.f; acc[nt][1] = 0.f; acc[nt][2] = 0.f; acc[nt][3] = 0.f;
    }
#pragma unroll
    for (int nt = 0; nt < 8; ++nt) {
        const unsigned short* brow = &Ws[(nt * 16 + (lane & 15)) * WS_STRIDE + kq];
#pragma unroll
        for (int kt = 0; kt < 4; ++kt) {
            short8 b = *reinterpret_cast<const short8*>(brow + kt * 32);
            acc[nt] = __builtin_amdgcn_mfma_f32_16x16x32_bf16(a[kt], b, acc[nt], 0, 0, 0);
        }
    }

    __syncthreads();   // prev tile's Ds readers done
    const int mlocal = wave * 16 + (lane >> 4) * 4;
    const int col = lane & 15;
#pragma unroll
    for (int r = 0; r < 4; ++r) {
        unsigned short* drow = &Ds[(mlocal + r) * DS_STRIDE + col];
#pragma unroll
        for (int nt = 0; nt < 8; ++nt)
            drow[nt * 16] = f2bf(acc[nt][r]);
    }
    __syncthreads();

    for (int idx = tid; idx < 64 * 16; idx += 256) {
        int row = idx >> 4;
        int chunk = idx & 15;
        int m = node0 + row;
        if (m < N) {
            uint4 v = *reinterpret_cast<const uint4*>(&Ds[row * DS_STRIDE + chunk * 8]);
            *reinterpret_cast<uint4*>(tf + (size_t)m * D + chunk * 8) = v;
        }
    }
}

// ---- gather-reduce for one 16-node group: out = relu(sum w*tf[src] + b) ----
__device__ __forceinline__ void gather16(
    const unsigned short* __restrict__ tf, const unsigned* __restrict__ ep,
    const int* __restrict__ cnt, const float* __restrict__ bias,
    float* __restrict__ out, int N, int g)
{
    int node = g * 16 + (threadIdx.x >> 4);
    if (node >= N) return;
    const int lane = threadIdx.x & 15;
    const int c = lane << 3;               // 8 bf16 per lane
    const unsigned* col = ep + node;       // stride N per plane
    int end = cnt[node];
    end = end < CAP ? end : CAP;
    int p = 0;
    float a0 = 0.f, a1 = 0.f, a2 = 0.f, a3 = 0.f;
    float a4 = 0.f, a5 = 0.f, a6 = 0.f, a7 = 0.f;

#define ACC8(Q, W)                                       \
    a0 += __uint_as_float((Q).x << 16) * (W);            \
    a1 += __uint_as_float((Q).x & 0xffff0000u) * (W);    \
    a2 += __uint_as_float((Q).y << 16) * (W);            \
    a3 += __uint_as_float((Q).y & 0xffff0000u) * (W);    \
    a4 += __uint_as_float((Q).z << 16) * (W);            \
    a5 += __uint_as_float((Q).z & 0xffff0000u) * (W);    \
    a6 += __uint_as_float((Q).w << 16) * (W);            \
    a7 += __uint_as_float((Q).w & 0xffff0000u) * (W);

    for (; p + 7 < end; p += 8) {
        unsigned r[8];
#pragma unroll
        for (int j = 0; j < 8; ++j) r[j] = col[(size_t)(p + j) * N];
        uint4 q[8];
        float wv[8];
#pragma unroll
        for (int j = 0; j < 8; ++j) {
            q[j] = *reinterpret_cast<const uint4*>(tf + (size_t)(r[j] & 0xffffu) * D + c);
            wv[j] = __uint_as_float(r[j] & 0xffff0000u);
        }
#pragma unroll
        for (int j = 0; j < 8; ++j) { ACC8(q[j], wv[j]) }
    }
    for (; p + 3 < end; p += 4) {
        unsigned r[4];
#pragma unroll
        for (int j = 0; j < 4; ++j) r[j] = col[(size_t)(p + j) * N];
        uint4 q[4];
        float wv[4];
#pragma unroll
        for (int j = 0; j < 4; ++j) {
            q[j] = *reinterpret_cast<const uint4*>(tf + (size_t)(r[j] & 0xffffu) * D + c);
            wv[j] = __uint_as_float(r[j] & 0xffff0000u);
        }
#pragma unroll
        for (int j = 0; j < 4; ++j) { ACC8(q[j], wv[j]) }
    }
    for (; p < end; ++p) {
        unsigned r = col[(size_t)p * N];
        float wv = __uint_as_float(r & 0xffff0000u);
        uint4 q = *reinterpret_cast<const uint4*>(tf + (size_t)(r & 0xffffu) * D + c);
        ACC8(q, wv)
    }
#undef ACC8

    const float4 bv0 = *reinterpret_cast<const float4*>(bias + c);
    const float4 bv1 = *reinterpret_cast<const float4*>(bias + c + 4);
    float4 r0, r1;
    r0.x = fmaxf(a0 + bv0.x, 0.f);
    r0.y = fmaxf(a1 + bv0.y, 0.f);
    r0.z = fmaxf(a2 + bv0.z, 0.f);
    r0.w = fmaxf(a3 + bv0.w, 0.f);
    r1.x = fmaxf(a4 + bv1.x, 0.f);
    r1.y = fmaxf(a5 + bv1.y, 0.f);
    r1.z = fmaxf(a6 + bv1.z, 0.f);
    r1.w = fmaxf(a7 + bv1.w, 0.f);
    float* o = out + (size_t)node * D + c;
    *reinterpret_cast<float4*>(o) = r0;
    *reinterpret_cast<float4*>(o + 4) = r1;
}

// ================= cooperative mega-kernel: partition -> csr+gemm -> gather =================
// 768 blocks exactly co-resident (52 KB LDS -> 3/CU x 256 CU). Two grid.sync()s replace
// three launch boundaries + their gaps. gemm tiles claimed via global atomic counter so
// the 391 csr blocks rebalance into gemm work when they finish.
__global__ __launch_bounds__(256) void gcn_mega(
    const float* __restrict__ feat, const float* __restrict__ Wm,
    unsigned short* __restrict__ tf,
    const int* __restrict__ src, const int* __restrict__ dst,
    const float* __restrict__ w,
    int* __restrict__ gcnt, uint2* __restrict__ binned,
    unsigned* __restrict__ ep, int* __restrict__ cnt,
    int* __restrict__ tcnt,
    const float* __restrict__ bias, float* __restrict__ out,
    int N, int E)
{
    __shared__ char smem[52224] __attribute__((aligned(16)));
    __shared__ int tsh;
    cg::grid_group grid = cg::this_grid();
    const int nfb = (N + 127) >> 7;
    const int nchunks = (E + P1_CHUNK - 1) / P1_CHUNK;
    const int ntiles = (N + 63) >> 6;

    // phase 1: partition edges into coarse bins
    for (int c = blockIdx.x; c < nchunks; c += gridDim.x)
        partition_chunk(smem, src, dst, w, gcnt, binned, N, E, c);
    grid.sync();

    // phase 2: csr build (first nfb blocks) then dynamic-counter gemm (all blocks)
    if ((int)blockIdx.x < nfb)
        csr_build_bin(smem, binned, gcnt, ep, cnt, N, blockIdx.x);
    gemm_stage_W(smem, Wm);
    for (;;) {
        if (threadIdx.x == 0) tsh = atomicAdd(tcnt, 1);
        __syncthreads();
        int t = tsh;
        if (t >= ntiles) break;
        gemm_tile(smem, feat, tf, N, t);
    }
    grid.sync();

    // phase 3: gather
    const int ngr = (N + 15) >> 4;
    for (int g = blockIdx.x; g < ngr; g += gridDim.x)
        gather16(tf, ep, cnt, bias, out, N, g);
}

// ================= fallback path (r7 structure, sort-free) =================
__global__ __launch_bounds__(256) void edge_partition(
    const int* __restrict__ src, const int* __restrict__ dst,
    const float* __restrict__ w, int* __restrict__ gcnt,
    uint2* __restrict__ binned, int N, int E)
{
    __shared__ char smem[2048 + P1_CHUNK * 8] __attribute__((aligned(16)));
    partition_chunk(smem, src, dst, w, gcnt, binned, N, E, blockIdx.x);
}

__global__ __launch_bounds__(256) void csr_gemm(
    const uint2* __restrict__ binned, const int* __restrict__ gcnt,
    unsigned* __restrict__ ep, int* __restrict__ cnt,
    const float* __restrict__ feat, const float* __restrict__ Wm,
    unsigned short* __restrict__ tf, int N)
{
    __shared__ char smem[52224] __attribute__((aligned(16)));
    const int nfb = (N + 127) >> 7;
    if ((int)blockIdx.x < nfb) {
        csr_build_bin(smem, binned, gcnt, ep, cnt, N, blockIdx.x);
        return;
    }
    gemm_stage_W(smem, Wm);
    const int ntiles = (N + 63) >> 6;
    for (int t = blockIdx.x - nfb; t < ntiles; t += GEMM_BLOCKS)
        gemm_tile(smem, feat, tf, N, t);
}

__global__ __launch_bounds__(256) void csr_gather_bf16(
    const unsigned short* __restrict__ tf, const unsigned* __restrict__ ep,
    const int* __restrict__ cnt, const float* __restrict__ bias,
    float* __restrict__ out, int N)
{
    gather16(tf, ep, cnt, bias, out, N, blockIdx.x);
}

// ================= tier-1 fallback: atomic scatter + fp32 GEMM =================
__global__ __launch_bounds__(256) void edge_scatter(
    const float* __restrict__ feat, const int* __restrict__ src,
    const int* __restrict__ dst, const float* __restrict__ w,
    float* __restrict__ agg, int E)
{
    long long idx = (long long)blockIdx.x * 256 + threadIdx.x;
    int e = (int)(idx >> 5);
    if (e >= E) return;
    int c = ((int)idx & 31) << 2;
    int s = src[e];
    int d = dst[e];
    float wv = w[e];
    const float4 f = *reinterpret_cast<const float4*>(feat + (size_t)s * D + c);
    float* a = agg + (size_t)d * D + c;
    atomicAdd(a + 0, f.x * wv);
    atomicAdd(a + 1, f.y * wv);
    atomicAdd(a + 2, f.z * wv);
    atomicAdd(a + 3, f.w * wv);
}

__global__ __launch_bounds__(256) void node_linear(
    const float* __restrict__ in, const float* __restrict__ Wm,
    const float* __restrict__ bias, float* __restrict__ out, int N)
{
    __shared__ float Bs[64 * BS_STRIDE];
    __shared__ float As[TILE_M * AS_STRIDE];
    const int tid = threadIdx.x;
    const int tx = tid & 15;
    const int ty = tid >> 4;
    const int node0 = blockIdx.x * TILE_M;
    float acc[4][8];
#pragma unroll
    for (int i = 0; i < 4; ++i)
#pragma unroll
        for (int jj = 0; jj < 8; ++jj) acc[i][jj] = 0.0f;
    for (int kh = 0; kh < 2; ++kh) {
        const int kbase = kh * 64;
        for (int i = tid; i < 128 * 64; i += 256) {
            int j = i >> 6, k = i & 63;
            Bs[k * BS_STRIDE + j] = Wm[j * 128 + kbase + k];
        }
        for (int i = tid; i < TILE_M * 64; i += 256) {
            int m = i >> 6, k = i & 63;
            int n = node0 + m;
            As[m * AS_STRIDE + k] = (n < N) ? in[(size_t)n * D + kbase + k] : 0.0f;
        }
        __syncthreads();
        for (int k0 = 0; k0 < 64; k0 += 4) {
            float a[4][4];
#pragma unroll
            for (int i = 0; i < 4; ++i) {
                const float4 v = *reinterpret_cast<const float4*>(&As[(ty * 4 + i) * AS_STRIDE + k0]);
                a[i][0] = v.x; a[i][1] = v.y; a[i][2] = v.z; a[i][3] = v.w;
            }
#pragma unroll
            for (int kk = 0; kk < 4; ++kk) {
                float bv[8];
#pragma unroll
                for (int jj = 0; jj < 8; ++jj) bv[jj] = Bs[(k0 + kk) * BS_STRIDE + tx + 16 * jj];
#pragma unroll
                for (int i = 0; i < 4; ++i)
#pragma unroll
                    for (int jj = 0; jj < 8; ++jj) acc[i][jj] += a[i][kk] * bv[jj];
            }
        }
        __syncthreads();
    }
    float bv[8];
#pragma unroll
    for (int jj = 0; jj < 8; ++jj) bv[jj] = bias[tx + 16 * jj];
#pragma unroll
    for (int i = 0; i < 4; ++i) {
        int n = node0 + ty * 4 + i;
        if (n < N) {
            float* o = out + (size_t)n * D;
#pragma unroll
            for (int jj = 0; jj < 8; ++jj) {
                float v = acc[i][jj] + bv[jj];
                o[tx + 16 * jj] = v > 0.0f ? v : 0.0f;
            }
        }
    }
}

extern "C" void kernel_launch(void* const* d_in, const int* in_sizes, int n_in,
                              void* d_out, int out_size, void* d_ws, size_t ws_size,
                              hipStream_t stream) {
    const float* feat = (const float*)d_in[0];
    const int*   src  = (const int*)d_in[1];
    const int*   dst  = (const int*)d_in[2];
    const float* w    = (const float*)d_in[3];
    const float* Wm   = (const float*)d_in[4];
    const float* bias = (const float*)d_in[5];
    float* out = (float*)d_out;

    const int N = in_sizes[0] / D;   // 50000
    const int E = in_sizes[1];       // 800000

    const int ncb = (N + 511) >> CSH;      // coarse bins (98)
    const int nfb = (N + 127) >> 7;        // fine bins   (391)
    const int nchunks = (E + P1_CHUNK - 1) / P1_CHUNK;

    const size_t ep_b     = (size_t)N * CAP * 4;              // plane-major CSR, 12.8 MB
    const size_t cnt_b    = (size_t)N * sizeof(int);
    const size_t tf_b     = (size_t)N * D * 2;
    const size_t binned_b = (size_t)ncb * CBCAP * sizeof(uint2);  // 12.8 MB
    const size_t gcnt_b   = 192 * sizeof(int);                // gcnt[128] + tcnt + pad
    auto align_up = [](size_t x) { return (x + 255) & ~(size_t)255; };

    const size_t need_full = align_up(ep_b) + align_up(cnt_b) + align_up(tf_b) +
                             align_up(binned_b) + align_up(gcnt_b);

    // fast path: src ids fit 16 bits, padded-CSR sane, ws fits
    if (ws_size >= need_full && N <= 65536 &&
        (long long)E <= (long long)N * (CAP / 4)) {
        char* p = (char*)d_ws;
        unsigned* ep     = (unsigned*)p;       p += align_up(ep_b);
        int*      cnt    = (int*)p;            p += align_up(cnt_b);
        unsigned short* tf = (unsigned short*)p; p += align_up(tf_b);
        uint2*    binned = (uint2*)p;          p += align_up(binned_b);
        int*      gcnt   = (int*)p;
        int*      tcnt   = gcnt + 128;

        (void)hipMemsetAsync(gcnt, 0, 132 * sizeof(int), stream);

        int Nv = N, Ev = E;
        void* kargs[] = { (void*)&feat, (void*)&Wm, (void*)&tf, (void*)&src,
                          (void*)&dst, (void*)&w, (void*)&gcnt, (void*)&binned,
                          (void*)&ep, (void*)&cnt, (void*)&tcnt, (void*)&bias,
                          (void*)&out, (void*)&Nv, (void*)&Ev };
        hipError_t err = hipLaunchCooperativeKernel(
            (const void*)gcn_mega, dim3(MEGA_BLOCKS), dim3(256), kargs, 0, stream);
        if (err != hipSuccess) {
            // cooperative unavailable (e.g. under capture restrictions) -> r7 path
            edge_partition<<<nchunks, 256, 0, stream>>>(src, dst, w, gcnt, binned, N, E);
            csr_gemm<<<nfb + GEMM_BLOCKS, 256, 0, stream>>>(binned, gcnt, ep, cnt,
                                                            feat, Wm, tf, N);
            csr_gather_bf16<<<(N + 15) / 16, 256, 0, stream>>>(tf, ep, cnt, bias, out, N);
        }
    } else {
        // fallback: atomic scatter into out, then in-place fp32 linear
        (void)hipMemsetAsync(out, 0, (size_t)N * D * sizeof(float), stream);
        long long st = (long long)E * 32;
        edge_scatter<<<(int)((st + 255) / 256), 256, 0, stream>>>(feat, src, dst, w, out, E);
        node_linear<<<(N + TILE_M - 1) / TILE_M, 256, 0, stream>>>(out, Wm, bias, out, N);
    }
}

// Round 10
// 142.196 us; speedup vs baseline: 2.3791x; 2.3791x over previous
//
#include <hip/hip_runtime.h>

#define D 128
#define TILE_M 64
#define BS_STRIDE 129
#define AS_STRIDE 68
#define WS_STRIDE 136   // shorts; 272 B rows -> 16 B aligned, banks spread
#define DS_STRIDE 136
#define P1_BLOCKS 512       // partition role blocks in k1
#define GEMM_BLOCKS 768     // gemm role blocks in k1
#define CAP 64              // padded CSR row capacity (max degree ~35; 64 = 12 sigma)
#define CSH 8               // coarse bin = dst>>8 (256 nodes/bin); N<=65536 -> <=256 bins
#define CBCAP 8192          // coarse-bin capacity (mean 4096 @ E=800K, +64 sigma slack)
#define P1_CHUNK 1564       // edges per partition chunk; grouped[] = 12512 B LDS

typedef __attribute__((ext_vector_type(8))) short short8;
typedef __attribute__((ext_vector_type(4))) float floatx4;
typedef __attribute__((ext_vector_type(4))) unsigned short ushortx4;

__device__ __forceinline__ unsigned short f2bf(float f) {
    unsigned u = __float_as_uint(f);
    u += 0x7fffu + ((u >> 16) & 1u);   // round-to-nearest-even
    return (unsigned short)(u >> 16);
}

// r21: r20's cooperative mega REVERTED (grid.sync on 8 non-coherent XCDs flushes the
// per-XCD L2s at every phase boundary: FETCH 75->110MB, 245us). Back to stream-order
// dependencies only. New structure: k1 = partition || gemm role-fusion (independent
// work overlapped); k2 = csr-build-in-LDS + gather fused per 64-node bin -- the padded
// CSR (ep/cnt) NEVER touches global memory (kills 12.8MB write + ~16MB read + one
// launch boundary). Coarse bins = 256 nodes so k2's bin-scan amplification is 4x
// (26MB, L3-resident).

// ---- partition one chunk of edges into coarse dst-bins (LDS radix) ----
// smem: hist[256] | startb[256] | cursor[256] | gbase[256] | grouped[P1_CHUNK]  (16.6 KB)
__device__ __forceinline__ void partition_chunk(
    char* smem, const int* __restrict__ src, const int* __restrict__ dst,
    const float* __restrict__ w, int* __restrict__ gcnt,
    uint2* __restrict__ binned, int N, int E, int cidx)
{
    int* hist      = reinterpret_cast<int*>(smem);
    int* startb    = reinterpret_cast<int*>(smem + 1024);
    int* cursor    = reinterpret_cast<int*>(smem + 2048);
    int* gbase     = reinterpret_cast<int*>(smem + 3072);
    uint2* grouped = reinterpret_cast<uint2*>(smem + 4096);   // P1_CHUNK*8 B
    const int tid = threadIdx.x;
    const int ncb = (N + 255) >> CSH;
    const int base = cidx * P1_CHUNK;
    int lim = E - base;
    if (lim > P1_CHUNK) lim = P1_CHUNK;
    if (lim < 0) lim = 0;
    const int lim4 = lim & ~3;

    hist[tid] = 0;
    __syncthreads();
    for (int i = tid * 4; i < lim4; i += 1024) {
        const int4 d4 = *reinterpret_cast<const int4*>(dst + base + i);
        atomicAdd(&hist[d4.x >> CSH], 1);
        atomicAdd(&hist[d4.y >> CSH], 1);
        atomicAdd(&hist[d4.z >> CSH], 1);
        atomicAdd(&hist[d4.w >> CSH], 1);
    }
    for (int i = lim4 + tid; i < lim; i += 256)
        atomicAdd(&hist[dst[base + i] >> CSH], 1);
    __syncthreads();
    if (tid == 0) {
        int s = 0;
        for (int b = 0; b < ncb; ++b) { startb[b] = s; s += hist[b]; }
    }
    __syncthreads();
    if (tid < ncb) {
        gbase[tid]  = atomicAdd(&gcnt[tid], hist[tid]);   // only global atomics
        cursor[tid] = startb[tid];
    }
    __syncthreads();
    for (int i = tid * 4; i < lim4; i += 1024) {
        const int4   d4 = *reinterpret_cast<const int4*>(dst + base + i);
        const int4   s4 = *reinterpret_cast<const int4*>(src + base + i);
        const float4 w4 = *reinterpret_cast<const float4*>(w + base + i);
#pragma unroll
        for (int j = 0; j < 4; ++j) {
            int   d  = (j == 0) ? d4.x : (j == 1) ? d4.y : (j == 2) ? d4.z : d4.w;
            int   sj = (j == 0) ? s4.x : (j == 1) ? s4.y : (j == 2) ? s4.z : s4.w;
            float wj = (j == 0) ? w4.x : (j == 1) ? w4.y : (j == 2) ? w4.z : w4.w;
            unsigned rec = ((unsigned)f2bf(wj) << 16) | (unsigned)sj;
            int g = atomicAdd(&cursor[d >> CSH], 1);
            grouped[g] = make_uint2((unsigned)d, rec);
        }
    }
    for (int i = lim4 + tid; i < lim; i += 256) {
        int e = base + i;
        int d = dst[e];
        unsigned rec = ((unsigned)f2bf(w[e]) << 16) | (unsigned)src[e];
        int g = atomicAdd(&cursor[d >> CSH], 1);
        grouped[g] = make_uint2((unsigned)d, rec);
    }
    __syncthreads();
    // flush: contiguous per-bin runs (avg ~8 edges = 64B = one line)
    for (int i = tid; i < lim; i += 256) {
        uint2 v = grouped[i];
        int b = (int)(v.x >> CSH);
        int off = gbase[b] + (i - startb[b]);
        if (off < CBCAP)
            binned[(size_t)b * CBCAP + (size_t)off] = v;
    }
    __syncthreads();   // protect smem reuse by next chunk
}

// ---- stage W (bf16) into LDS ----
__device__ __forceinline__ void gemm_stage_W(char* smem, const float* __restrict__ Wm)
{
    unsigned short* Ws = reinterpret_cast<unsigned short*>(smem);
    for (int idx = threadIdx.x; idx < 128 * 128 / 4; idx += 256) {
        int r = idx >> 5;
        int c = (idx & 31) * 4;
        const float4 v = reinterpret_cast<const float4*>(Wm)[idx];
        ushortx4 s;
        s[0] = f2bf(v.x); s[1] = f2bf(v.y); s[2] = f2bf(v.z); s[3] = f2bf(v.w);
        *reinterpret_cast<ushortx4*>(&Ws[r * WS_STRIDE + c]) = s;
    }
    __syncthreads();
}

// ---- one 64-node MFMA tile: tf[node0..node0+63] = bf16(feat @ W^T) ----
__device__ __forceinline__ void gemm_tile(
    char* smem, const float* __restrict__ feat,
    unsigned short* __restrict__ tf, int N, int t)
{
    unsigned short* Ws = reinterpret_cast<unsigned short*>(smem);
    unsigned short* Ds = reinterpret_cast<unsigned short*>(smem + 34816);
    const int tid = threadIdx.x;
    const int lane = tid & 63;
    const int wave = tid >> 6;
    const int kq = (lane >> 4) * 8;
    const int node0 = t * 64;
    const int mr = node0 + wave * 16 + (lane & 15);
    const float* arow = feat + (size_t)(mr < N ? mr : (N - 1)) * D + kq;

    short8 a[4];
#pragma unroll
    for (int kt = 0; kt < 4; ++kt) {
        const float* p = arow + kt * 32;
        const float4 lo = *reinterpret_cast<const float4*>(p);
        const float4 hi = *reinterpret_cast<const float4*>(p + 4);
        short8 v;
        v[0] = (short)f2bf(lo.x); v[1] = (short)f2bf(lo.y);
        v[2] = (short)f2bf(lo.z); v[3] = (short)f2bf(lo.w);
        v[4] = (short)f2bf(hi.x); v[5] = (short)f2bf(hi.y);
        v[6] = (short)f2bf(hi.z); v[7] = (short)f2bf(hi.w);
        a[kt] = v;
    }

    floatx4 acc[8];
#pragma unroll
    for (int nt = 0; nt < 8; ++nt) {
        acc[nt][0] = 0.f; acc[nt][1] = 0.f; acc[nt][2] = 0.f; acc[nt][3] = 0.f;
    }
#pragma unroll
    for (int nt = 0; nt < 8; ++nt) {
        const unsigned short* brow = &Ws[(nt * 16 + (lane & 15)) * WS_STRIDE + kq];
#pragma unroll
        for (int kt = 0; kt < 4; ++kt) {
            short8 b = *reinterpret_cast<const short8*>(brow + kt * 32);
            acc[nt] = __builtin_amdgcn_mfma_f32_16x16x32_bf16(a[kt], b, acc[nt], 0, 0, 0);
        }
    }

    __syncthreads();   // prev tile's Ds readers done
    const int mlocal = wave * 16 + (lane >> 4) * 4;
    const int col = lane & 15;
#pragma unroll
    for (int r = 0; r < 4; ++r) {
        unsigned short* drow = &Ds[(mlocal + r) * DS_STRIDE + col];
#pragma unroll
        for (int nt = 0; nt < 8; ++nt)
            drow[nt * 16] = f2bf(acc[nt][r]);
    }
    __syncthreads();

    for (int idx = tid; idx < 64 * 16; idx += 256) {
        int row = idx >> 4;
        int chunk = idx & 15;
        int m = node0 + row;
        if (m < N) {
            uint4 v = *reinterpret_cast<const uint4*>(&Ds[row * DS_STRIDE + chunk * 8]);
            *reinterpret_cast<uint4*>(tf + (size_t)m * D + chunk * 8) = v;
        }
    }
}

// ================= k1: partition (512 blocks) || gemm (768 blocks) =================
// Mutually independent work; role-fusion overlaps partition's atomic/latency chains
// under gemm's MFMA waves. 52 KB LDS -> 3 blocks/CU, all 1280 blocks ~co-resident.
__global__ __launch_bounds__(256) void part_gemm(
    const int* __restrict__ src, const int* __restrict__ dst,
    const float* __restrict__ w, int* __restrict__ gcnt,
    uint2* __restrict__ binned,
    const float* __restrict__ feat, const float* __restrict__ Wm,
    unsigned short* __restrict__ tf, int N, int E)
{
    __shared__ char smem[52224] __attribute__((aligned(16)));
    if ((int)blockIdx.x < P1_BLOCKS) {
        const int nchunks = (E + P1_CHUNK - 1) / P1_CHUNK;
        for (int ci = blockIdx.x; ci < nchunks; ci += P1_BLOCKS)
            partition_chunk(smem, src, dst, w, gcnt, binned, N, E, ci);
        return;
    }
    gemm_stage_W(smem, Wm);
    const int ntiles = (N + 63) >> 6;
    for (int t = blockIdx.x - P1_BLOCKS; t < ntiles; t += GEMM_BLOCKS)
        gemm_tile(smem, feat, tf, N, t);
}

// ================= k2: csr-build-in-LDS + gather, one block per 64-node bin =================
// Build rowsT[pos][node] (16 KB LDS) from the coarse-bin list (4x filter, L3-resident),
// then gather DIRECTLY from LDS records -- ep/cnt never hit global. 16 groups x 16
// lanes; each group handles 4 nodes; 8 planes unrolled -> 8 independent tf loads in
// flight per lane. (N+63)/64 = 782 blocks @ ~16.5 KB -> ~3/CU co-resident.
__global__ __launch_bounds__(256) void csr_gather_fused(
    const uint2* __restrict__ binned, const int* __restrict__ gcnt,
    const unsigned short* __restrict__ tf, const float* __restrict__ bias,
    float* __restrict__ out, int N)
{
    __shared__ unsigned rowsT[CAP * 64];   // 16384 B
    __shared__ int lcnt[64];
    const int tid = threadIdx.x;
    const int fb = blockIdx.x;
    const int d0 = fb << 6;
    const int cb = fb >> 2;                // 256-node coarse bin

    if (tid < 64) lcnt[tid] = 0;
    __syncthreads();
    int len = gcnt[cb];
    len = len < CBCAP ? len : CBCAP;
    const uint2* bp = binned + (size_t)cb * CBCAP;
    const int len2 = len & ~1;
    for (int i = tid * 2; i < len2; i += 512) {     // uint4 = 2 records
        const uint4 v2 = *reinterpret_cast<const uint4*>(bp + i);
        int da = (int)v2.x;
        if ((da >> 6) == fb) {
            int pos = atomicAdd(&lcnt[da & 63], 1);
            if (pos < CAP) rowsT[pos * 64 + (da & 63)] = v2.y;
        }
        int db = (int)v2.z;
        if ((db >> 6) == fb) {
            int pos = atomicAdd(&lcnt[db & 63], 1);
            if (pos < CAP) rowsT[pos * 64 + (db & 63)] = v2.w;
        }
    }
    for (int i = len2 + tid; i < len; i += 256) {
        uint2 v = bp[i];
        int d = (int)v.x;
        if ((d >> 6) == fb) {
            int pos = atomicAdd(&lcnt[d & 63], 1);
            if (pos < CAP) rowsT[pos * 64 + (d & 63)] = v.y;
        }
    }
    __syncthreads();

    const int g = tid >> 4;
    const int lane = tid & 15;
    const int c = lane << 3;               // 8 bf16 per lane
    const float4 bv0 = *reinterpret_cast<const float4*>(bias + c);
    const float4 bv1 = *reinterpret_cast<const float4*>(bias + c + 4);

#define ACC8(Q, W)                                       \
    a0 += __uint_as_float((Q).x << 16) * (W);            \
    a1 += __uint_as_float((Q).x & 0xffff0000u) * (W);    \
    a2 += __uint_as_float((Q).y << 16) * (W);            \
    a3 += __uint_as_float((Q).y & 0xffff0000u) * (W);    \
    a4 += __uint_as_float((Q).z << 16) * (W);            \
    a5 += __uint_as_float((Q).z & 0xffff0000u) * (W);    \
    a6 += __uint_as_float((Q).w << 16) * (W);            \
    a7 += __uint_as_float((Q).w & 0xffff0000u) * (W);

#pragma unroll
    for (int it = 0; it < 4; ++it) {
        const int j = g + (it << 4);
        const int node = d0 + j;
        if (node >= N) break;              // contiguous tail
        int end = lcnt[j];
        end = end < CAP ? end : CAP;
        const unsigned* col = &rowsT[j];   // stride 64 per plane, LDS broadcast
        float a0 = 0.f, a1 = 0.f, a2 = 0.f, a3 = 0.f;
        float a4 = 0.f, a5 = 0.f, a6 = 0.f, a7 = 0.f;
        int p = 0;
        for (; p + 7 < end; p += 8) {
            unsigned r[8];
#pragma unroll
            for (int k = 0; k < 8; ++k) r[k] = col[(p + k) * 64];
            uint4 q[8];
            float wv[8];
#pragma unroll
            for (int k = 0; k < 8; ++k) {
                q[k] = *reinterpret_cast<const uint4*>(tf + (size_t)(r[k] & 0xffffu) * D + c);
                wv[k] = __uint_as_float(r[k] & 0xffff0000u);
            }
#pragma unroll
            for (int k = 0; k < 8; ++k) { ACC8(q[k], wv[k]) }
        }
        for (; p + 3 < end; p += 4) {
            unsigned r[4];
#pragma unroll
            for (int k = 0; k < 4; ++k) r[k] = col[(p + k) * 64];
            uint4 q[4];
            float wv[4];
#pragma unroll
            for (int k = 0; k < 4; ++k) {
                q[k] = *reinterpret_cast<const uint4*>(tf + (size_t)(r[k] & 0xffffu) * D + c);
                wv[k] = __uint_as_float(r[k] & 0xffff0000u);
            }
#pragma unroll
            for (int k = 0; k < 4; ++k) { ACC8(q[k], wv[k]) }
        }
        for (; p < end; ++p) {
            unsigned r = col[p * 64];
            float wv = __uint_as_float(r & 0xffff0000u);
            uint4 q = *reinterpret_cast<const uint4*>(tf + (size_t)(r & 0xffffu) * D + c);
            ACC8(q, wv)
        }
        float4 r0, r1;
        r0.x = fmaxf(a0 + bv0.x, 0.f);
        r0.y = fmaxf(a1 + bv0.y, 0.f);
        r0.z = fmaxf(a2 + bv0.z, 0.f);
        r0.w = fmaxf(a3 + bv0.w, 0.f);
        r1.x = fmaxf(a4 + bv1.x, 0.f);
        r1.y = fmaxf(a5 + bv1.y, 0.f);
        r1.z = fmaxf(a6 + bv1.z, 0.f);
        r1.w = fmaxf(a7 + bv1.w, 0.f);
        float* o = out + (size_t)node * D + c;
        *reinterpret_cast<float4*>(o) = r0;
        *reinterpret_cast<float4*>(o + 4) = r1;
    }
#undef ACC8
}

// ================= tier-1 fallback: atomic scatter + fp32 GEMM =================
__global__ __launch_bounds__(256) void edge_scatter(
    const float* __restrict__ feat, const int* __restrict__ src,
    const int* __restrict__ dst, const float* __restrict__ w,
    float* __restrict__ agg, int E)
{
    long long idx = (long long)blockIdx.x * 256 + threadIdx.x;
    int e = (int)(idx >> 5);
    if (e >= E) return;
    int c = ((int)idx & 31) << 2;
    int s = src[e];
    int d = dst[e];
    float wv = w[e];
    const float4 f = *reinterpret_cast<const float4*>(feat + (size_t)s * D + c);
    float* a = agg + (size_t)d * D + c;
    atomicAdd(a + 0, f.x * wv);
    atomicAdd(a + 1, f.y * wv);
    atomicAdd(a + 2, f.z * wv);
    atomicAdd(a + 3, f.w * wv);
}

__global__ __launch_bounds__(256) void node_linear(
    const float* __restrict__ in, const float* __restrict__ Wm,
    const float* __restrict__ bias, float* __restrict__ out, int N)
{
    __shared__ float Bs[64 * BS_STRIDE];
    __shared__ float As[TILE_M * AS_STRIDE];
    const int tid = threadIdx.x;
    const int tx = tid & 15;
    const int ty = tid >> 4;
    const int node0 = blockIdx.x * TILE_M;
    float acc[4][8];
#pragma unroll
    for (int i = 0; i < 4; ++i)
#pragma unroll
        for (int jj = 0; jj < 8; ++jj) acc[i][jj] = 0.0f;
    for (int kh = 0; kh < 2; ++kh) {
        const int kbase = kh * 64;
        for (int i = tid; i < 128 * 64; i += 256) {
            int j = i >> 6, k = i & 63;
            Bs[k * BS_STRIDE + j] = Wm[j * 128 + kbase + k];
        }
        for (int i = tid; i < TILE_M * 64; i += 256) {
            int m = i >> 6, k = i & 63;
            int n = node0 + m;
            As[m * AS_STRIDE + k] = (n < N) ? in[(size_t)n * D + kbase + k] : 0.0f;
        }
        __syncthreads();
        for (int k0 = 0; k0 < 64; k0 += 4) {
            float a[4][4];
#pragma unroll
            for (int i = 0; i < 4; ++i) {
                const float4 v = *reinterpret_cast<const float4*>(&As[(ty * 4 + i) * AS_STRIDE + k0]);
                a[i][0] = v.x; a[i][1] = v.y; a[i][2] = v.z; a[i][3] = v.w;
            }
#pragma unroll
            for (int kk = 0; kk < 4; ++kk) {
                float bv[8];
#pragma unroll
                for (int jj = 0; jj < 8; ++jj) bv[jj] = Bs[(k0 + kk) * BS_STRIDE + tx + 16 * jj];
#pragma unroll
                for (int i = 0; i < 4; ++i)
#pragma unroll
                    for (int jj = 0; jj < 8; ++jj) acc[i][jj] += a[i][kk] * bv[jj];
            }
        }
        __syncthreads();
    }
    float bv[8];
#pragma unroll
    for (int jj = 0; jj < 8; ++jj) bv[jj] = bias[tx + 16 * jj];
#pragma unroll
    for (int i = 0; i < 4; ++i) {
        int n = node0 + ty * 4 + i;
        if (n < N) {
            float* o = out + (size_t)n * D;
#pragma unroll
            for (int jj = 0; jj < 8; ++jj) {
                float v = acc[i][jj] + bv[jj];
                o[tx + 16 * jj] = v > 0.0f ? v : 0.0f;
            }
        }
    }
}

extern "C" void kernel_launch(void* const* d_in, const int* in_sizes, int n_in,
                              void* d_out, int out_size, void* d_ws, size_t ws_size,
                              hipStream_t stream) {
    const float* feat = (const float*)d_in[0];
    const int*   src  = (const int*)d_in[1];
    const int*   dst  = (const int*)d_in[2];
    const float* w    = (const float*)d_in[3];
    const float* Wm   = (const float*)d_in[4];
    const float* bias = (const float*)d_in[5];
    float* out = (float*)d_out;

    const int N = in_sizes[0] / D;   // 50000
    const int E = in_sizes[1];       // 800000

    const int ncb = (N + 255) >> CSH;      // coarse bins (196)
    const int nfb = (N + 63) >> 6;         // 64-node fine bins (782)

    const size_t tf_b     = (size_t)N * D * 2;                    // 12.8 MB
    const size_t binned_b = (size_t)ncb * CBCAP * sizeof(uint2);  // 12.85 MB
    const size_t gcnt_b   = 256 * sizeof(int);
    auto align_up = [](size_t x) { return (x + 255) & ~(size_t)255; };

    const size_t need_full = align_up(tf_b) + align_up(binned_b) + align_up(gcnt_b);

    // fast path: src ids fit 16 bits, padded rows sane, ws fits
    if (ws_size >= need_full && N <= 65536 &&
        (long long)E <= (long long)N * (CAP / 4)) {
        char* p = (char*)d_ws;
        unsigned short* tf = (unsigned short*)p; p += align_up(tf_b);
        uint2*    binned = (uint2*)p;            p += align_up(binned_b);
        int*      gcnt   = (int*)p;

        (void)hipMemsetAsync(gcnt, 0, gcnt_b, stream);
        part_gemm<<<P1_BLOCKS + GEMM_BLOCKS, 256, 0, stream>>>(
            src, dst, w, gcnt, binned, feat, Wm, tf, N, E);
        csr_gather_fused<<<nfb, 256, 0, stream>>>(binned, gcnt, tf, bias, out, N);
    } else {
        // fallback: atomic scatter into out, then in-place fp32 linear
        (void)hipMemsetAsync(out, 0, (size_t)N * D * sizeof(float), stream);
        long long st = (long long)E * 32;
        edge_scatter<<<(int)((st + 255) / 256), 256, 0, stream>>>(feat, src, dst, w, out, E);
        node_linear<<<(N + TILE_M - 1) / TILE_M, 256, 0, stream>>>(out, Wm, bias, out, N);
    }
}